// Round 9
// baseline (194.753 us; speedup 1.0000x reference)
//
#include <hip/hip_runtime.h>
#include <hip/hip_bf16.h>
#include <math.h>

// Problem constants
#define BQ 128
#define PP 256
#define MQ 16
#define MP 32
#define DD 768
#define MROWS (BQ*MQ)   // 2048
#define NROWS (PP*MP)   // 8192

typedef __bf16 bf16x8 __attribute__((ext_vector_type(8)));
typedef float  f32x4  __attribute__((ext_vector_type(4)));

// ---------- fp32 -> bf16 RTNE (both tensors in one launch) ----------
__device__ inline ushort bf16r(float f) {
    unsigned u = __float_as_uint(f);
    return (ushort)((u + 0x7FFFu + ((u >> 16) & 1u)) >> 16);
}

#define NQ4 (MROWS*DD/4)   // 393216
#define NP4 (NROWS*DD/4)   // 1572864

__global__ void conv_bf16_both(const float4* __restrict__ q, const float4* __restrict__ p,
                               ushort4* __restrict__ qb, ushort4* __restrict__ pb) {
    int idx = blockIdx.x * blockDim.x + threadIdx.x;
    const float4* in; ushort4* out; int i;
    if (idx < NQ4) { in = q; out = qb; i = idx; }
    else           { in = p; out = pb; i = idx - NQ4; }
    float4 x = in[i];
    ushort4 o;
    o.x = bf16r(x.x); o.y = bf16r(x.y); o.z = bf16r(x.z); o.w = bf16r(x.w);
    out[i] = o;
}

// ---------- barrier-free fused GEMM + selection ----------
// Each WAVE is self-sufficient: owns a 64x64 output tile, stages its own
// A(64xBK)+B(64xBK) into a PRIVATE 8 KB LDS slice, waits only on its own
// vmcnt (NO __syncthreads in the kernel). Waves desynchronize, so one wave's
// select (VALU/SALU) overlaps other waves' MFMA/DS/L2 staging (m114).
// R4-R8 showed the barriered structure is pinned at ~86 us by phase lockstep.
// Select: 12-bit keys (absmax-validated in R8), ballot+SALU counting
// (measured best, R5), complement trick (bottom_l = total - top_{n-l}).
#define BK 32
#define LDSU 32    // ushorts per staging row (64 B, unpadded for global_load_lds)

__device__ inline void load16_to_lds(const ushort* g, ushort* l) {
    __builtin_amdgcn_global_load_lds(
        (const __attribute__((address_space(1))) unsigned int*)(g),
        (__attribute__((address_space(3))) unsigned int*)(l),
        16, 0, 0);
}

__device__ inline float key_to_float(unsigned kk) {
    return (kk & 0x80000000u) ? __uint_as_float(kk & 0x7FFFFFFFu)
                              : __uint_as_float(~kk);
}

__device__ inline float softplus_f(float x) {
    return (x > 20.f) ? x : log1pf(expf(x));
}

__global__ __launch_bounds__(256) void gemm_select(const ushort* __restrict__ A,
                                                   const ushort* __restrict__ B,
                                                   const int* __restrict__ qm,
                                                   const int* __restrict__ pm,
                                                   const float* __restrict__ araw,
                                                   const float* __restrict__ braw,
                                                   float* __restrict__ logits) {
    __shared__ ushort sA[4][64 * LDSU];   // per-wave private 4 KB slices
    __shared__ ushort sB[4][64 * LDSU];

    const int tid  = threadIdx.x;
    const int lane = tid & 63;
    const int wid  = tid >> 6;              // 4 independent waves
    const int tmw  = blockIdx.y * 256 + wid * 64;  // wave's A row base
    const int tnw  = blockIdx.x * 64;              // wave's B row base (cols)
    const int bBase = blockIdx.y * 16 + wid * 4;   // 4 q-batches per wave
    const int pBase = blockIdx.x * 2;              // 2 passages per wave

    // ---- per-wave mask words
    unsigned qw[4]; int nq[4];
    #pragma unroll
    for (int t = 0; t < 4; ++t) {
        bool v = (lane < MQ) && (qm[(bBase + t) * MQ + lane] != 0);
        unsigned long long bal = __ballot(v);
        qw[t] = (unsigned)bal;
        nq[t] = __popcll(bal);
    }
    unsigned pw[2]; int np_[2];
    #pragma unroll
    for (int t = 0; t < 2; ++t) {
        bool v = (lane < MP) && (pm[(pBase + t) * MP + lane] != 0);
        unsigned long long bal = __ballot(v);
        pw[t] = (unsigned)bal;
        np_[t] = __popcll(bal);
    }

    // ---- GEMM phase (wave-private, no barriers)
    f32x4 acc[4][4];
    #pragma unroll
    for (int i = 0; i < 4; ++i)
        #pragma unroll
        for (int j = 0; j < 4; ++j) {
            f32x4 z = {0.f, 0.f, 0.f, 0.f};
            acc[i][j] = z;
        }

    const int lr  = lane >> 2;                               // row within 16-row chunk
    const int kcu = ((lane & 3) ^ ((lane >> 3) & 3)) << 3;   // swizzled logical k-offset
    const int r0    = lane & 15;
    const int q     = lane >> 4;
    const int physq = q ^ ((r0 >> 1) & 3);                   // R5 swizzle (0 conflicts measured)

    for (int k0 = 0; k0 < DD; k0 += BK) {
        // stage this wave's A 64 rows + B 64 rows (4 chunks of 16 rows each)
        #pragma unroll
        for (int c = 0; c < 4; ++c) {
            int row = c * 16 + lr;
            load16_to_lds(A + (size_t)(tmw + row) * DD + k0 + kcu, &sA[wid][c * 16 * LDSU]);
            load16_to_lds(B + (size_t)(tnw + row) * DD + k0 + kcu, &sB[wid][c * 16 * LDSU]);
        }
        // wait own LDS-DMA only (drains this wave's vmcnt; no cross-wave sync)
        __builtin_amdgcn_s_waitcnt(0);

        bf16x8 af[4], bfr[4];
        #pragma unroll
        for (int mi = 0; mi < 4; ++mi)
            af[mi] = *(const bf16x8*)(&sA[wid][(mi * 16 + r0) * LDSU + physq * 8]);
        #pragma unroll
        for (int ni = 0; ni < 4; ++ni)
            bfr[ni] = *(const bf16x8*)(&sB[wid][(ni * 16 + r0) * LDSU + physq * 8]);

        #pragma unroll
        for (int mi = 0; mi < 4; ++mi)
            #pragma unroll
            for (int ni = 0; ni < 4; ++ni)
                acc[mi][ni] = __builtin_amdgcn_mfma_f32_16x16x32_bf16(af[mi], bfr[ni], acc[mi][ni], 0, 0, 0);
    }

    // ---- selection: 8 pairs per wave from acc registers
    // C/D layout (m89): row=(lane>>4)*4+(t&3), col=(t>>2)*16+(lane&15)
    float aco = softplus_f(araw[0]);
    float bco = softplus_f(braw[0]);
    const int rowb = (lane >> 4) * 4;
    const int colb = lane & 15;

    #pragma unroll 1
    for (int pair = 0; pair < 8; ++pair) {
        // wave-uniform switch keeps acc indexing static
        f32x4 w0, w1; unsigned qwv, pwv; int nqv, npv;
        switch (pair) {
        case 0:  w0 = acc[0][0]; w1 = acc[0][1]; qwv = qw[0]; nqv = nq[0]; pwv = pw[0]; npv = np_[0]; break;
        case 1:  w0 = acc[0][2]; w1 = acc[0][3]; qwv = qw[0]; nqv = nq[0]; pwv = pw[1]; npv = np_[1]; break;
        case 2:  w0 = acc[1][0]; w1 = acc[1][1]; qwv = qw[1]; nqv = nq[1]; pwv = pw[0]; npv = np_[0]; break;
        case 3:  w0 = acc[1][2]; w1 = acc[1][3]; qwv = qw[1]; nqv = nq[1]; pwv = pw[1]; npv = np_[1]; break;
        case 4:  w0 = acc[2][0]; w1 = acc[2][1]; qwv = qw[2]; nqv = nq[2]; pwv = pw[0]; npv = np_[0]; break;
        case 5:  w0 = acc[2][2]; w1 = acc[2][3]; qwv = qw[2]; nqv = nq[2]; pwv = pw[1]; npv = np_[1]; break;
        case 6:  w0 = acc[3][0]; w1 = acc[3][1]; qwv = qw[3]; nqv = nq[3]; pwv = pw[0]; npv = np_[0]; break;
        default: w0 = acc[3][2]; w1 = acc[3][3]; qwv = qw[3]; nqv = nq[3]; pwv = pw[1]; npv = np_[1]; break;
        }

        int n  = nqv * npv;               // >= 1
        int k  = (4 * n) / 10; if (k < 1) k = 1;
        int m2 = n - (8 * n) / 10;        // complement rank, >= 1

        float v[8] = {w0[0], w0[1], w0[2], w0[3], w1[0], w1[1], w1[2], w1[3]};
        unsigned key[8];
        float tot = 0.f;
        #pragma unroll
        for (int t = 0; t < 8; ++t) {
            int row = rowb + (t & 3);
            int col = (t >> 2) * 16 + colb;
            unsigned uu = __float_as_uint(v[t]);
            unsigned kk = (uu & 0x80000000u) ? ~uu : (uu | 0x80000000u);
            bool val = (((qwv >> row) & 1u) != 0u) && (((pwv >> col) & 1u) != 0u);
            key[t] = val ? (kk >> 20) : 0u;   // 12-bit keys; valid >= 1
            if (val) tot += v[t];
        }

        // dual 12-bit MSB-first radix descent, ballot+SALU counting
        unsigned T1 = 0u, T2 = 0u;
        for (int bit = 11; bit >= 0; --bit) {
            unsigned c1 = T1 | (1u << bit);
            unsigned c2 = T2 | (1u << bit);
            int cnt1 = 0, cnt2 = 0;
            #pragma unroll
            for (int t = 0; t < 8; ++t) {
                cnt1 += __popcll(__ballot(key[t] >= c1));
                cnt2 += __popcll(__ballot(key[t] >= c2));
            }
            if (cnt1 >= k)  T1 = c1;
            if (cnt2 >= m2) T2 = c2;
        }

        // tie-corrected sums
        float S1 = 0.f, S2 = 0.f;
        int c1n = 0, c2n = 0;
        #pragma unroll
        for (int t = 0; t < 8; ++t) {
            if (key[t] > T1) S1 += v[t];
            if (key[t] > T2) S2 += v[t];
            c1n += __popcll(__ballot(key[t] > T1));
            c2n += __popcll(__ballot(key[t] > T2));
        }
        #pragma unroll
        for (int off = 32; off > 0; off >>= 1) {
            S1  += __shfl_xor(S1,  off, 64);
            S2  += __shfl_xor(S2,  off, 64);
            tot += __shfl_xor(tot, off, 64);
        }

        float f1 = key_to_float(T1 << 20);
        float f2 = key_to_float(T2 << 20);
        float top = S1 + (float)(k  - c1n) * f1;
        float cmp = S2 + (float)(m2 - c2n) * f2;
        float bot = tot - cmp;

        if (lane == 0) {
            int bl = pair >> 1, pl = pair & 1;
            logits[(bBase + bl) * PP + (pBase + pl)] = aco * top - bco * bot;
        }
    }
}

// ---------- loss = mean_b (lse(logits[b,:]) - logits[b,b]) ----------
__global__ __launch_bounds__(256) void loss_kernel(const float* __restrict__ logits,
                                                   float* __restrict__ loss_out) {
    __shared__ float warr[4];
    const int lane = threadIdx.x & 63;
    const int wid  = threadIdx.x >> 6;
    float acc = 0.f;
    for (int r = wid; r < BQ; r += 4) {
        const float* row = logits + r * PP;
        float x0 = row[lane], x1 = row[lane + 64], x2 = row[lane + 128], x3 = row[lane + 192];
        float m = fmaxf(fmaxf(x0, x1), fmaxf(x2, x3));
        #pragma unroll
        for (int off = 32; off > 0; off >>= 1)
            m = fmaxf(m, __shfl_xor(m, off, 64));
        float s = expf(x0 - m) + expf(x1 - m) + expf(x2 - m) + expf(x3 - m);
        #pragma unroll
        for (int off = 32; off > 0; off >>= 1)
            s += __shfl_xor(s, off, 64);
        float lse = m + logf(s);
        float diag = row[r];
        acc += (lse - diag);
    }
    if (lane == 0) warr[wid] = acc;
    __syncthreads();
    if (threadIdx.x == 0)
        loss_out[0] = (warr[0] + warr[1] + warr[2] + warr[3]) / (float)BQ;
}

extern "C" void kernel_launch(void* const* d_in, const int* in_sizes, int n_in,
                              void* d_out, int out_size, void* d_ws, size_t ws_size,
                              hipStream_t stream) {
    const float* q  = (const float*)d_in[0];
    const float* pe = (const float*)d_in[1];
    const int*   qm = (const int*)d_in[2];
    const int*   pm = (const int*)d_in[3];
    const float* ar = (const float*)d_in[4];
    const float* br = (const float*)d_in[5];
    float* out = (float*)d_out;           // [0] = loss, [1..32768] = logits

    // workspace: qb | pb (bf16 copies)
    char* ws = (char*)d_ws;
    ushort* qb  = (ushort*)ws;
    ushort* pb  = (ushort*)(ws + (size_t)MROWS * DD * 2);

    // 1) convert fp32 -> bf16 (single launch for both tensors)
    conv_bf16_both<<<(NQ4 + NP4) / 256, 256, 0, stream>>>(
        (const float4*)q, (const float4*)pe, (ushort4*)qb, (ushort4*)pb);

    // 2) fused barrier-free sim-GEMM + dual top-k -> logits
    dim3 gg(NROWS / 64, MROWS / 256, 1);   // (128, 8) = 1024 blocks, 4096 waves
    gemm_select<<<gg, 256, 0, stream>>>(qb, pb, qm, pm, ar, br, out + 1);

    // 3) loss
    loss_kernel<<<1, 256, 0, stream>>>(out + 1, out);
}

// Round 10
// 183.696 us; speedup vs baseline: 1.0602x; 1.0602x over previous
//
#include <hip/hip_runtime.h>
#include <hip/hip_bf16.h>
#include <math.h>

// Problem constants
#define BQ 128
#define PP 256
#define MQ 16
#define MP 32
#define DD 768
#define MROWS (BQ*MQ)   // 2048
#define NROWS (PP*MP)   // 8192

typedef __bf16 bf16x8 __attribute__((ext_vector_type(8)));
typedef float  f32x4  __attribute__((ext_vector_type(4)));

// ---------- fp32 -> bf16 RTNE (both tensors in one launch) ----------
__device__ inline ushort bf16r(float f) {
    unsigned u = __float_as_uint(f);
    return (ushort)((u + 0x7FFFu + ((u >> 16) & 1u)) >> 16);
}

#define NQ4 (MROWS*DD/4)   // 393216
#define NP4 (NROWS*DD/4)   // 1572864

__global__ void conv_bf16_both(const float4* __restrict__ q, const float4* __restrict__ p,
                               ushort4* __restrict__ qb, ushort4* __restrict__ pb) {
    int idx = blockIdx.x * blockDim.x + threadIdx.x;
    const float4* in; ushort4* out; int i;
    if (idx < NQ4) { in = q; out = qb; i = idx; }
    else           { in = p; out = pb; i = idx - NQ4; }
    float4 x = in[i];
    ushort4 o;
    o.x = bf16r(x.x); o.y = bf16r(x.y); o.z = bf16r(x.z); o.w = bf16r(x.w);
    out[i] = o;
}

// ---------- DPP wave-64 reductions (pure VALU: no SALU chains, no DS pipe) ----
// row_shr 1/2/4/8 then row_bcast15 (rows 1,3) + row_bcast31 (rows 2,3):
// lane 63 ends with the full-wave sum. bound_ctrl=1 -> OOB lanes read 0.
__device__ inline int dpp_reduce_i32(int v) {
    v += __builtin_amdgcn_update_dpp(0, v, 0x111, 0xF, 0xF, true);  // row_shr:1
    v += __builtin_amdgcn_update_dpp(0, v, 0x112, 0xF, 0xF, true);  // row_shr:2
    v += __builtin_amdgcn_update_dpp(0, v, 0x114, 0xF, 0xF, true);  // row_shr:4
    v += __builtin_amdgcn_update_dpp(0, v, 0x118, 0xF, 0xF, true);  // row_shr:8
    v += __builtin_amdgcn_update_dpp(0, v, 0x142, 0xA, 0xF, true);  // row_bcast:15
    v += __builtin_amdgcn_update_dpp(0, v, 0x143, 0xC, 0xF, true);  // row_bcast:31
    return v;   // lane 63 = total
}

__device__ inline float dpp_reduce_f32(float x) {
    int m;
    m = __builtin_amdgcn_update_dpp(0, __float_as_int(x), 0x111, 0xF, 0xF, true); x += __int_as_float(m);
    m = __builtin_amdgcn_update_dpp(0, __float_as_int(x), 0x112, 0xF, 0xF, true); x += __int_as_float(m);
    m = __builtin_amdgcn_update_dpp(0, __float_as_int(x), 0x114, 0xF, 0xF, true); x += __int_as_float(m);
    m = __builtin_amdgcn_update_dpp(0, __float_as_int(x), 0x118, 0xF, 0xF, true); x += __int_as_float(m);
    m = __builtin_amdgcn_update_dpp(0, __float_as_int(x), 0x142, 0xA, 0xF, true); x += __int_as_float(m);
    m = __builtin_amdgcn_update_dpp(0, __float_as_int(x), 0x143, 0xC, 0xF, true); x += __int_as_float(m);
    return x;   // lane 63 = total
}

// ---------- fused GEMM (64x128 bf16 MFMA tile) + register-resident selection ----
// R5 GEMM skeleton (best measured). Selection: 12-bit keys (validated R8),
// complement trick, per-lane VALU counting + DPP reduction per radix bit
// (R7/R8 analysis: ballot counting serializes ~25 us on the CU-shared scalar
// unit; DPP keeps the whole descent on the per-SIMD vector pipe).
#define BM 64
#define BN 128
#define BK 32
#define LDSU 32    // ushorts per staging row (64 B, unpadded for global_load_lds)

__device__ inline void load16_to_lds(const ushort* g, ushort* l) {
    __builtin_amdgcn_global_load_lds(
        (const __attribute__((address_space(1))) unsigned int*)(g),
        (__attribute__((address_space(3))) unsigned int*)(l),
        16, 0, 0);
}

__device__ inline float key_to_float(unsigned kk) {
    return (kk & 0x80000000u) ? __uint_as_float(kk & 0x7FFFFFFFu)
                              : __uint_as_float(~kk);
}

__device__ inline float softplus_f(float x) {
    return (x > 20.f) ? x : log1pf(expf(x));
}

__global__ __launch_bounds__(256) void gemm_select(const ushort* __restrict__ A,
                                                   const ushort* __restrict__ B,
                                                   const int* __restrict__ qm,
                                                   const int* __restrict__ pm,
                                                   const float* __restrict__ araw,
                                                   const float* __restrict__ braw,
                                                   float* __restrict__ logits) {
    __shared__ ushort sA[BM * LDSU];   // 4 KB
    __shared__ ushort sB[BN * LDSU];   // 8 KB

    const int tid  = threadIdx.x;
    const int lane = tid & 63;
    const int wid  = tid >> 6;        // 4 waves, 2x2 over 64x128
    const int wr   = wid >> 1;
    const int wc   = wid & 1;
    const int tileM = blockIdx.y * BM;
    const int tileN = blockIdx.x * BN;
    const int bBase = blockIdx.y * 4;
    const int pBase = blockIdx.x * 4;

    // ---- per-wave mask words: 2 q-blocks, 2 p-blocks
    unsigned qw[2]; int nq[2];
    #pragma unroll
    for (int t = 0; t < 2; ++t) {
        bool v = (lane < MQ) && (qm[(bBase + wr * 2 + t) * MQ + lane] != 0);
        unsigned long long bal = __ballot(v);
        qw[t] = (unsigned)bal;
        nq[t] = __popcll(bal);
    }
    unsigned pw[2]; int np_[2];
    #pragma unroll
    for (int t = 0; t < 2; ++t) {
        bool v = (lane < MP) && (pm[(pBase + wc * 2 + t) * MP + lane] != 0);
        unsigned long long bal = __ballot(v);
        pw[t] = (unsigned)bal;
        np_[t] = __popcll(bal);
    }

    // ---- GEMM phase (R5 verbatim)
    f32x4 acc[2][4];
    #pragma unroll
    for (int i = 0; i < 2; ++i)
        #pragma unroll
        for (int j = 0; j < 4; ++j) {
            f32x4 z = {0.f, 0.f, 0.f, 0.f};
            acc[i][j] = z;
        }

    const int lr  = lane >> 2;
    const int kcu = ((lane & 3) ^ ((lane >> 3) & 3)) << 3;
    const int r0    = lane & 15;
    const int q     = lane >> 4;
    const int physq = q ^ ((r0 >> 1) & 3);

    for (int k0 = 0; k0 < DD; k0 += BK) {
        {
            int rowA = wid * 16 + lr;
            load16_to_lds(A + (size_t)(tileM + rowA) * DD + k0 + kcu, &sA[wid * 16 * LDSU]);
            #pragma unroll
            for (int c = 0; c < 2; ++c) {
                int chunk = wid * 2 + c;
                int rowB  = chunk * 16 + lr;
                load16_to_lds(B + (size_t)(tileN + rowB) * DD + k0 + kcu, &sB[chunk * 16 * LDSU]);
            }
        }
        __syncthreads();

        bf16x8 af[2], bfr[4];
        #pragma unroll
        for (int mi = 0; mi < 2; ++mi)
            af[mi] = *(const bf16x8*)(&sA[(wr * 32 + mi * 16 + r0) * LDSU + physq * 8]);
        #pragma unroll
        for (int ni = 0; ni < 4; ++ni)
            bfr[ni] = *(const bf16x8*)(&sB[(wc * 64 + ni * 16 + r0) * LDSU + physq * 8]);

        #pragma unroll
        for (int mi = 0; mi < 2; ++mi)
            #pragma unroll
            for (int ni = 0; ni < 4; ++ni)
                acc[mi][ni] = __builtin_amdgcn_mfma_f32_16x16x32_bf16(af[mi], bfr[ni], acc[mi][ni], 0, 0, 0);
        __syncthreads();
    }

    // ---- selection: 4 pairs/wave from acc regs
    // C/D layout (m89): row=(lane>>4)*4+(t&3), col=(t>>2)*16+(lane&15)
    float aco = softplus_f(araw[0]);
    float bco = softplus_f(braw[0]);
    const int rowb = (lane >> 4) * 4;
    const int colb = lane & 15;

    #pragma unroll 1
    for (int pair = 0; pair < 4; ++pair) {
        f32x4 w0, w1; unsigned qwv, pwv; int nqv, npv;
        switch (pair) {
        case 0:  w0 = acc[0][0]; w1 = acc[0][1]; qwv = qw[0]; nqv = nq[0]; pwv = pw[0]; npv = np_[0]; break;
        case 1:  w0 = acc[0][2]; w1 = acc[0][3]; qwv = qw[0]; nqv = nq[0]; pwv = pw[1]; npv = np_[1]; break;
        case 2:  w0 = acc[1][0]; w1 = acc[1][1]; qwv = qw[1]; nqv = nq[1]; pwv = pw[0]; npv = np_[0]; break;
        default: w0 = acc[1][2]; w1 = acc[1][3]; qwv = qw[1]; nqv = nq[1]; pwv = pw[1]; npv = np_[1]; break;
        }

        int n  = nqv * npv;               // >= 1
        int k  = (4 * n) / 10; if (k < 1) k = 1;
        int m2 = n - (8 * n) / 10;        // complement rank, >= 1

        float v[8] = {w0[0], w0[1], w0[2], w0[3], w1[0], w1[1], w1[2], w1[3]};
        unsigned key[8];
        float tot = 0.f;
        #pragma unroll
        for (int t = 0; t < 8; ++t) {
            int row = rowb + (t & 3);
            int col = (t >> 2) * 16 + colb;
            unsigned uu = __float_as_uint(v[t]);
            unsigned kk = (uu & 0x80000000u) ? ~uu : (uu | 0x80000000u);
            bool val = (((qwv >> row) & 1u) != 0u) && (((pwv >> col) & 1u) != 0u);
            key[t] = val ? (kk >> 20) : 0u;   // 12-bit keys; valid >= 1
            if (val) tot += v[t];
        }

        // dual 12-bit MSB-first radix descent: per-lane packed count (both
        // chains in one u32) + one DPP reduction + readlane per bit.
        unsigned T1 = 0u, T2 = 0u;
        for (int bit = 11; bit >= 0; --bit) {
            unsigned c1 = T1 | (1u << bit);
            unsigned c2 = T2 | (1u << bit);
            int cnt = 0;
            #pragma unroll
            for (int t = 0; t < 8; ++t) {
                cnt += (key[t] >= c1) ? 1 : 0;
                cnt += (key[t] >= c2) ? 0x10000 : 0;
            }
            cnt = dpp_reduce_i32(cnt);
            unsigned total = (unsigned)__builtin_amdgcn_readlane(cnt, 63);
            if ((int)(total & 0xFFFFu) >= k)  T1 = c1;
            if ((int)(total >> 16)    >= m2) T2 = c2;
        }

        // tie-corrected sums (DPP-reduced; valid in lane 63)
        float S1 = 0.f, S2 = 0.f;
        int pc = 0;
        #pragma unroll
        for (int t = 0; t < 8; ++t) {
            if (key[t] > T1) { S1 += v[t]; pc += 1; }
            if (key[t] > T2) { S2 += v[t]; pc += 0x10000; }
        }
        S1  = dpp_reduce_f32(S1);
        S2  = dpp_reduce_f32(S2);
        tot = dpp_reduce_f32(tot);
        pc  = dpp_reduce_i32(pc);

        if (lane == 63) {
            int c1n = pc & 0xFFFF, c2n = ((unsigned)pc) >> 16;
            float f1 = key_to_float(T1 << 20);
            float f2 = key_to_float(T2 << 20);
            float top = S1 + (float)(k  - c1n) * f1;
            float cmp = S2 + (float)(m2 - c2n) * f2;
            float bot = tot - cmp;
            int bl = pair >> 1, pl = pair & 1;
            logits[(bBase + wr * 2 + bl) * PP + (pBase + wc * 2 + pl)] = aco * top - bco * bot;
        }
    }
}

// ---------- loss = mean_b (lse(logits[b,:]) - logits[b,b]) ----------
__global__ __launch_bounds__(256) void loss_kernel(const float* __restrict__ logits,
                                                   float* __restrict__ loss_out) {
    __shared__ float warr[4];
    const int lane = threadIdx.x & 63;
    const int wid  = threadIdx.x >> 6;
    float acc = 0.f;
    for (int r = wid; r < BQ; r += 4) {
        const float* row = logits + r * PP;
        float x0 = row[lane], x1 = row[lane + 64], x2 = row[lane + 128], x3 = row[lane + 192];
        float m = fmaxf(fmaxf(x0, x1), fmaxf(x2, x3));
        #pragma unroll
        for (int off = 32; off > 0; off >>= 1)
            m = fmaxf(m, __shfl_xor(m, off, 64));
        float s = expf(x0 - m) + expf(x1 - m) + expf(x2 - m) + expf(x3 - m);
        #pragma unroll
        for (int off = 32; off > 0; off >>= 1)
            s += __shfl_xor(s, off, 64);
        float lse = m + logf(s);
        float diag = row[r];
        acc += (lse - diag);
    }
    if (lane == 0) warr[wid] = acc;
    __syncthreads();
    if (threadIdx.x == 0)
        loss_out[0] = (warr[0] + warr[1] + warr[2] + warr[3]) / (float)BQ;
}

extern "C" void kernel_launch(void* const* d_in, const int* in_sizes, int n_in,
                              void* d_out, int out_size, void* d_ws, size_t ws_size,
                              hipStream_t stream) {
    const float* q  = (const float*)d_in[0];
    const float* pe = (const float*)d_in[1];
    const int*   qm = (const int*)d_in[2];
    const int*   pm = (const int*)d_in[3];
    const float* ar = (const float*)d_in[4];
    const float* br = (const float*)d_in[5];
    float* out = (float*)d_out;           // [0] = loss, [1..32768] = logits

    // workspace: qb | pb (bf16 copies)
    char* ws = (char*)d_ws;
    ushort* qb  = (ushort*)ws;
    ushort* pb  = (ushort*)(ws + (size_t)MROWS * DD * 2);

    // 1) convert fp32 -> bf16 (single launch for both tensors)
    conv_bf16_both<<<(NQ4 + NP4) / 256, 256, 0, stream>>>(
        (const float4*)q, (const float4*)pe, (ushort4*)qb, (ushort4*)pb);

    // 2) fused sim-GEMM + dual top-k -> logits
    dim3 gg(NROWS / BN, MROWS / BM, 1);   // (64, 32) = 2048 blocks = 8/CU
    gemm_select<<<gg, 256, 0, stream>>>(qb, pb, qm, pm, ar, br, out + 1);

    // 3) loss
    loss_kernel<<<1, 256, 0, stream>>>(out + 1, out);
}